// Round 19
// baseline (931.908 us; speedup 1.0000x reference)
//
#include <hip/hip_runtime.h>
#include <hip/hip_bf16.h>

// HeteroGATv2: 3 node types x 50000 nodes, 7 edge types x 800000 edges,
// 2 GATv2 layers (H=64), softmax head (4 classes) on node type 0.
//
// R19: gat_row re-geometried to 8-lane subgroups x 8 features (ushort8 16B
// gathers). Per-feature VALU is invariant, but per-edge-group issues halve:
// gathers (1 VMEM covers 8 edges/wave), score reduce (3 shfl vs 4), exp2
// (quarter-rate pipe, 1 issue per 8 edges), s-acc, src-shfl, addr math.
// R18 counters justified: gat_row 44.5us x14 = 72% of total, VALU 57% =
// issue-throughput-bound; arithmetic says ~12% issue cut.
// All other kernels identical to R18.

#define N_NODES 50000
#define NEDGE   800000
#define HDIM    64
#define DIN     32
#define NROWS   (7 * N_NODES)          // 350000 global rows (type-major)
#define CROWS   512                    // rows per coarse bucket
#define NCB     684                    // ceil(NROWS/CROWS)
#define TILE1   8192                   // edges per k1/pass1 block
#define NBLK1   684                    // ceil(7*NEDGE/TILE1)
#define K2IT    3                      // ceil(NBLK1/256)
#define SCAP    10240                  // part2 LDS staging cap

typedef __hip_bfloat16 bf16;
typedef short short8v __attribute__((ext_vector_type(8)));
typedef unsigned short ushort8v __attribute__((ext_vector_type(8)));
typedef float f32x4 __attribute__((ext_vector_type(4)));

__device__ __forceinline__ float ldf(const void* p, size_t i, int bf) {
    return bf ? __bfloat162float(((const bf16*)p)[i]) : ((const float*)p)[i];
}
__device__ __forceinline__ unsigned short f2bf(float f) {
    bf16 b = __float2bfloat16(f);
    return *(unsigned short*)&b;
}
__device__ __forceinline__ float bf2f(unsigned short u) {
    return __uint_as_float((unsigned)u << 16);
}

// flag[0] = 1 if x is bf16, 0 if f32.
__global__ void detect_kernel(const unsigned short* __restrict__ x, int* __restrict__ flag)
{
    __shared__ int sbad[256];
    int bad = 0;
    for (int i = threadIdx.x; i < 4096; i += 256) {
        unsigned short u = x[i];
        int ex = (u >> 7) & 0xff;
        bool zero = (u & 0x7fffu) == 0;
        if (!zero && (ex < 80 || ex > 140)) bad++;
    }
    sbad[threadIdx.x] = bad;
    __syncthreads();
    for (int s = 128; s > 0; s >>= 1) {
        if (threadIdx.x < s) sbad[threadIdx.x] += sbad[threadIdx.x + s];
        __syncthreads();
    }
    if (threadIdx.x == 0) flag[0] = (sbad[0] < 64) ? 1 : 0;
}

// ---------------- radix-partition CSR build (full path) ----------------

__global__ __launch_bounds__(1024) void k1_count_kernel(const int* __restrict__ edges,
                                                        int* __restrict__ cnt2d)
{
    __shared__ int lcount[NCB];
    for (int i = threadIdx.x; i < NCB; i += 1024) lcount[i] = 0;
    __syncthreads();
    int g0 = blockIdx.x * TILE1;
    #pragma unroll
    for (int k = 0; k < TILE1 / 1024; ++k) {
        int g = g0 + k * 1024 + threadIdx.x;
        if (g < 7 * NEDGE) {
            int t = g / NEDGE, i = g - t * NEDGE;
            int d = edges[(size_t)t * 2 * NEDGE + NEDGE + i];
            int r = t * N_NODES + d;
            atomicAdd(&lcount[r >> 9], 1);
        }
    }
    __syncthreads();
    for (int i = threadIdx.x; i < NCB; i += 1024)
        cnt2d[(size_t)i * NBLK1 + blockIdx.x] = lcount[i];
}

__global__ __launch_bounds__(256) void k2_colscan_kernel(int* __restrict__ cnt2d,
                                                         int* __restrict__ cbase)
{
    __shared__ int sv[256];
    int t = threadIdx.x;
    int* col = cnt2d + (size_t)blockIdx.x * NBLK1;
    int a[K2IT]; int s = 0;
    #pragma unroll
    for (int k = 0; k < K2IT; ++k) {
        int i = t * K2IT + k;
        a[k] = (i < NBLK1) ? col[i] : 0;
        s += a[k];
    }
    sv[t] = s; __syncthreads();
    for (int off = 1; off < 256; off <<= 1) {
        int v = (t >= off) ? sv[t - off] : 0; __syncthreads();
        sv[t] += v; __syncthreads();
    }
    int excl = sv[t] - s;
    #pragma unroll
    for (int k = 0; k < K2IT; ++k) {
        int i = t * K2IT + k;
        if (i < NBLK1) { col[i] = excl; excl += a[k]; }
    }
    if (t == 255) cbase[blockIdx.x] = sv[255];
}

__global__ __launch_bounds__(256) void k3_cscan_kernel(int* __restrict__ cbase,
                                                       int* __restrict__ P)
{
    __shared__ int sv[256];
    int t = threadIdx.x;
    int a[3]; int s = 0;
    #pragma unroll
    for (int k = 0; k < 3; ++k) {
        int i = t * 3 + k;
        a[k] = (i < NCB) ? cbase[i] : 0;
        s += a[k];
    }
    sv[t] = s; __syncthreads();
    for (int off = 1; off < 256; off <<= 1) {
        int v = (t >= off) ? sv[t - off] : 0; __syncthreads();
        sv[t] += v; __syncthreads();
    }
    int excl = sv[t] - s;
    #pragma unroll
    for (int k = 0; k < 3; ++k) {
        int i = t * 3 + k;
        if (i < NCB) { cbase[i] = excl; excl += a[k]; }
    }
    if (t == 255) { cbase[NCB] = sv[255]; P[NROWS] = sv[255]; }
}

__global__ __launch_bounds__(1024) void part1_kernel(const int* __restrict__ edges,
                                                     const int* __restrict__ cnt2d,
                                                     const int* __restrict__ cbase,
                                                     unsigned* __restrict__ buf)
{
    __shared__ int lcur[NCB];
    for (int i = threadIdx.x; i < NCB; i += 1024)
        lcur[i] = cbase[i] + cnt2d[(size_t)i * NBLK1 + blockIdx.x];
    __syncthreads();
    int g0 = blockIdx.x * TILE1;
    #pragma unroll
    for (int k = 0; k < TILE1 / 1024; ++k) {
        int g = g0 + k * 1024 + threadIdx.x;
        if (g < 7 * NEDGE) {
            int t = g / NEDGE, i = g - t * NEDGE;
            int s = edges[(size_t)t * 2 * NEDGE + i];
            int d = edges[(size_t)t * 2 * NEDGE + NEDGE + i];
            int r = t * N_NODES + d;
            int pos = atomicAdd(&lcur[r >> 9], 1);
            buf[pos] = ((unsigned)(r & 511) << 16) | (unsigned)s;
        }
    }
}

__global__ __launch_bounds__(256) void part2_kernel(const unsigned* __restrict__ buf,
                                                    const int* __restrict__ cbase,
                                                    int* __restrict__ P,
                                                    int* __restrict__ col_src)
{
    __shared__ int fcnt[CROWS];
    __shared__ int fpos[CROWS];
    __shared__ int sv[256];
    __shared__ int stage[SCAP];
    int b = blockIdx.x;
    int t = threadIdx.x;
    int start = cbase[b], end = cbase[b + 1];
    int cnt = end - start;
    fcnt[2 * t] = 0; fcnt[2 * t + 1] = 0;
    __syncthreads();
    for (int i = start + t; i < end; i += 256)
        atomicAdd(&fcnt[buf[i] >> 16], 1);
    __syncthreads();
    int a0 = fcnt[2 * t], a1 = fcnt[2 * t + 1];
    int s = a0 + a1;
    sv[t] = s; __syncthreads();
    for (int off = 1; off < 256; off <<= 1) {
        int v = (t >= off) ? sv[t - off] : 0; __syncthreads();
        sv[t] += v; __syncthreads();
    }
    int excl = sv[t] - s;
    fpos[2 * t] = excl; fpos[2 * t + 1] = excl + a0;
    int r0 = b * CROWS;
    int rows_in = NROWS - r0; if (rows_in > CROWS) rows_in = CROWS;
    if (2 * t < rows_in)     P[r0 + 2 * t]     = start + excl;
    if (2 * t + 1 < rows_in) P[r0 + 2 * t + 1] = start + excl + a0;
    __syncthreads();
    if (cnt <= SCAP) {
        for (int i = start + t; i < end; i += 256) {
            unsigned v = buf[i];
            int pos = atomicAdd(&fpos[v >> 16], 1);
            stage[pos] = (int)(v & 0xffffu);
        }
        __syncthreads();
        for (int i = t; i < cnt; i += 256)
            col_src[start + i] = stage[i];
    } else {
        for (int i = start + t; i < end; i += 256) {
            unsigned v = buf[i];
            int pos = start + atomicAdd(&fpos[v >> 16], 1);
            col_src[pos] = (int)(v & 0xffffu);
        }
    }
}

// ---------------- fallback CSR build (ws-limited) ----------------

__global__ __launch_bounds__(256) void hist_kernel(const int* __restrict__ edges,
                                                   int* __restrict__ cnt, int ntypes)
{
    int g = blockIdx.x * 256 + threadIdx.x;
    if (g >= ntypes * NEDGE) return;
    int t = g / NEDGE, i = g - t * NEDGE;
    int d = edges[(size_t)t * 2 * NEDGE + NEDGE + i];
    atomicAdd(&cnt[t * N_NODES + d], 1);
}

__global__ __launch_bounds__(256) void scanA_kernel(const int* __restrict__ cnt,
                                                    int* __restrict__ bsums, int n)
{
    __shared__ int lds[256];
    int tid = threadIdx.x;
    int base = blockIdx.x * 2048 + tid * 8;
    int s = 0;
    #pragma unroll
    for (int k = 0; k < 8; ++k) { int i = base + k; if (i < n) s += cnt[i]; }
    lds[tid] = s;
    __syncthreads();
    for (int o = 128; o > 0; o >>= 1) {
        if (tid < o) lds[tid] += lds[tid + o];
        __syncthreads();
    }
    if (tid == 0) bsums[blockIdx.x] = lds[0];
}

__global__ __launch_bounds__(256) void scanB_kernel(const int* __restrict__ bsums,
                                                    int* __restrict__ boffs, int nb,
                                                    int* __restrict__ P, int n)
{
    __shared__ int lds[256];
    int tid = threadIdx.x;
    int v = (tid < nb) ? bsums[tid] : 0;
    lds[tid] = v;
    __syncthreads();
    for (int off = 1; off < 256; off <<= 1) {
        int t2 = (tid >= off) ? lds[tid - off] : 0;
        __syncthreads();
        lds[tid] += t2;
        __syncthreads();
    }
    if (tid < nb) boffs[tid] = lds[tid] - v;
    if (tid == 255) P[n] = lds[255];
}

__global__ __launch_bounds__(256) void scanC_kernel(const int* __restrict__ cnt,
                                                    const int* __restrict__ boffs,
                                                    int* __restrict__ P,
                                                    int* __restrict__ cursor, int n)
{
    __shared__ int lds[256];
    int tid = threadIdx.x;
    int base = blockIdx.x * 2048 + tid * 8;
    int v[8];
    int s = 0;
    #pragma unroll
    for (int k = 0; k < 8; ++k) {
        int i = base + k;
        int c = (i < n) ? cnt[i] : 0;
        v[k] = s;
        s += c;
    }
    lds[tid] = s;
    __syncthreads();
    for (int off = 1; off < 256; off <<= 1) {
        int t2 = (tid >= off) ? lds[tid - off] : 0;
        __syncthreads();
        lds[tid] += t2;
        __syncthreads();
    }
    int off0 = boffs[blockIdx.x] + (lds[tid] - s);
    #pragma unroll
    for (int k = 0; k < 8; ++k) {
        int i = base + k;
        if (i < n) { int val = off0 + v[k]; P[i] = val; cursor[i] = val; }
    }
}

__global__ __launch_bounds__(256) void scatter1_kernel(const int* __restrict__ et,
                                                       int* __restrict__ cursor,
                                                       int* __restrict__ col_src)
{
    int i = blockIdx.x * 256 + threadIdx.x;
    if (i >= NEDGE) return;
    int s = et[i], d = et[NEDGE + i];
    int pos = atomicAdd(&cursor[d], 1);
    col_src[pos] = s;
}

// ---------------- bf16 converts ----------------

__global__ __launch_bounds__(256) void cvt_feat_kernel(const void* __restrict__ in,
                                                       int bfmode, const int* __restrict__ flag,
                                                       unsigned short* __restrict__ out, size_t n)
{
    int bf = bfmode < 0 ? flag[0] : bfmode;
    size_t i = ((size_t)blockIdx.x * 256 + threadIdx.x) * 4;
    if (i + 3 < n) {
        ushort4 o;
        o.x = f2bf(ldf(in, i + 0, bf));
        o.y = f2bf(ldf(in, i + 1, bf));
        o.z = f2bf(ldf(in, i + 2, bf));
        o.w = f2bf(ldf(in, i + 3, bf));
        *(ushort4*)(out + i) = o;
    } else {
        for (size_t j = i; j < n; ++j) out[j] = f2bf(ldf(in, j, bf));
    }
}

__global__ void cvt_w_kernel(const void* __restrict__ WlB, const void* __restrict__ WlF,
                             const void* __restrict__ WrB, const void* __restrict__ WrF,
                             const int* __restrict__ flag, unsigned short* __restrict__ wt, int K)
{
    int bf = flag[0];
    int t = blockIdx.x, side = blockIdx.y;
    const void* W = side ? (bf ? WrB : WrF) : (bf ? WlB : WlF);
    unsigned short* o = wt + ((size_t)t * 2 + side) * 64 * K;
    for (int idx = threadIdx.x; idx < 64 * K; idx += 256) {
        int n = idx / K, k = idx - n * K;
        o[idx] = f2bf(ldf(W, (size_t)t * K * 64 + (size_t)k * 64 + n, bf));
    }
}

// ---------------- MFMA lin GEMM: [50000 x K] @ [K x 64] + bias -> bf16 ------
template<int K>
__global__ __launch_bounds__(256) void gemm_lin_t(
    const unsigned short* __restrict__ fb, int srcT, int dstT,
    const unsigned short* __restrict__ wt,
    const void* blB, const void* blF, const void* brB, const void* brF,
    const int* __restrict__ flag,
    unsigned short* __restrict__ xl, unsigned short* __restrict__ xr)
{
    int side = blockIdx.y;
    int bf = flag[0];
    const unsigned short* A = fb + (size_t)(side ? dstT : srcT) * N_NODES * K;
    const unsigned short* W = wt + (size_t)side * 64 * K;
    const void* bias = side ? (bf ? brB : brF) : (bf ? blB : blF);
    unsigned short* out = side ? xr : xl;

    int wave = threadIdx.x >> 6;
    int lane = threadIdx.x & 63;
    int m0 = blockIdx.x * 64 + wave * 16;
    if (m0 >= N_NODES) return;
    int lg = lane >> 4;
    int lr = lane & 15;

    short8v afrag[K / 32];
    #pragma unroll
    for (int ks = 0; ks < K / 32; ++ks)
        afrag[ks] = *(const short8v*)(A + (size_t)(m0 + lr) * K + ks * 32 + lg * 8);

    f32x4 acc0 = {0.f, 0.f, 0.f, 0.f};
    f32x4 acc1 = {0.f, 0.f, 0.f, 0.f};
    f32x4 acc2 = {0.f, 0.f, 0.f, 0.f};
    f32x4 acc3 = {0.f, 0.f, 0.f, 0.f};
    #pragma unroll
    for (int ks = 0; ks < K / 32; ++ks) {
        short8v b0 = *(const short8v*)(W + (size_t)(0 * 16 + lr) * K + ks * 32 + lg * 8);
        short8v b1 = *(const short8v*)(W + (size_t)(1 * 16 + lr) * K + ks * 32 + lg * 8);
        short8v b2 = *(const short8v*)(W + (size_t)(2 * 16 + lr) * K + ks * 32 + lg * 8);
        short8v b3 = *(const short8v*)(W + (size_t)(3 * 16 + lr) * K + ks * 32 + lg * 8);
        acc0 = __builtin_amdgcn_mfma_f32_16x16x32_bf16(afrag[ks], b0, acc0, 0, 0, 0);
        acc1 = __builtin_amdgcn_mfma_f32_16x16x32_bf16(afrag[ks], b1, acc1, 0, 0, 0);
        acc2 = __builtin_amdgcn_mfma_f32_16x16x32_bf16(afrag[ks], b2, acc2, 0, 0, 0);
        acc3 = __builtin_amdgcn_mfma_f32_16x16x32_bf16(afrag[ks], b3, acc3, 0, 0, 0);
    }
    #pragma unroll
    for (int nt = 0; nt < 4; ++nt) {
        f32x4 a = nt == 0 ? acc0 : nt == 1 ? acc1 : nt == 2 ? acc2 : acc3;
        int n = nt * 16 + lr;
        float bb = ldf(bias, n, bf);
        #pragma unroll
        for (int r = 0; r < 4; ++r)
            out[(size_t)(m0 + lg * 4 + r) * HDIM + n] = f2bf(a[r] + bb);
    }
}

// ---------------- fallback linear transforms (write bf16) ----------------

#define FMA4(acc, f, i) acc += (f).x * w[4*(i)] + (f).y * w[4*(i)+1] \
                             + (f).z * w[4*(i)+2] + (f).w * w[4*(i)+3]
#define FMAI(acc, u, i) acc += __uint_as_float(((unsigned)(u)) << 16) * w[2*(i)] \
                             + __uint_as_float(((unsigned)(u)) & 0xffff0000u) * w[2*(i)+1]

template<int BF>
__global__ __launch_bounds__(256) void lin_d32_t(
    const void* fLb, const void* fLf, const void* fRb, const void* fRf,
    const void* wLb, const void* wLf, const void* wRb, const void* wRf,
    const void* bLb, const void* bLf, const void* bRb, const void* bRf,
    const int* __restrict__ flag,
    unsigned short* __restrict__ xl, unsigned short* __restrict__ xr)
{
    if (flag[0] != BF) return;
    int side = blockIdx.y;
    const void* W    = side ? (BF ? wRb : wRf) : (BF ? wLb : wLf);
    const void* b    = side ? (BF ? bRb : bRf) : (BF ? bLb : bLf);
    const void* feat = side ? (BF ? fRb : fRf) : (BF ? fLb : fLf);
    unsigned short* out = side ? xr : xl;
    int tid = threadIdx.x;
    int h = tid & 63;
    int slot = tid >> 6;
    float w[DIN];
    #pragma unroll
    for (int d = 0; d < DIN; ++d)
        w[d] = BF ? __bfloat162float(((const bf16*)W)[d * HDIM + h])
                  : ((const float*)W)[d * HDIM + h];
    float bias = BF ? __bfloat162float(((const bf16*)b)[h]) : ((const float*)b)[h];
    int base = blockIdx.x * 32;
    #pragma unroll
    for (int nn = 0; nn < 8; ++nn) {
        int node = base + nn * 4 + slot;
        int nc = node < N_NODES ? node : N_NODES - 1;
        float a0 = bias, a1 = 0.f, a2 = 0.f, a3 = 0.f;
        if (BF) {
            const int4* fp = (const int4*)((const bf16*)feat + (size_t)nc * DIN);
            int4 q0 = fp[0], q1 = fp[1], q2 = fp[2], q3 = fp[3];
            FMAI(a0, q0.x, 0);  FMAI(a1, q0.y, 1);  FMAI(a2, q0.z, 2);  FMAI(a3, q0.w, 3);
            FMAI(a0, q1.x, 4);  FMAI(a1, q1.y, 5);  FMAI(a2, q1.z, 6);  FMAI(a3, q1.w, 7);
            FMAI(a0, q2.x, 8);  FMAI(a1, q2.y, 9);  FMAI(a2, q2.z, 10); FMAI(a3, q2.w, 11);
            FMAI(a0, q3.x, 12); FMAI(a1, q3.y, 13); FMAI(a2, q3.z, 14); FMAI(a3, q3.w, 15);
        } else {
            const float4* f4 = (const float4*)((const float*)feat + (size_t)nc * DIN);
            float4 f0 = f4[0], f1 = f4[1], f2 = f4[2], f3 = f4[3];
            float4 f5 = f4[4], f6 = f4[5], f7 = f4[6], f8 = f4[7];
            FMA4(a0, f0, 0); FMA4(a1, f1, 1); FMA4(a2, f2, 2); FMA4(a3, f3, 3);
            FMA4(a0, f5, 4); FMA4(a1, f6, 5); FMA4(a2, f7, 6); FMA4(a3, f8, 7);
        }
        if (node < N_NODES)
            out[(size_t)node * HDIM + h] = f2bf((a0 + a1) + (a2 + a3));
    }
}

template<int BF>
__global__ __launch_bounds__(256) void lin_d64_t(
    const float* __restrict__ fL, const float* __restrict__ fR,
    const void* wLb, const void* wLf, const void* wRb, const void* wRf,
    const void* bLb, const void* bLf, const void* bRb, const void* bRf,
    const int* __restrict__ flag,
    unsigned short* __restrict__ xl, unsigned short* __restrict__ xr)
{
    if (flag[0] != BF) return;
    int side = blockIdx.y;
    const void* W = side ? (BF ? wRb : wRf) : (BF ? wLb : wLf);
    const void* b = side ? (BF ? bRb : bRf) : (BF ? bLb : bLf);
    const float* feat = side ? fR : fL;
    unsigned short* out = side ? xr : xl;
    int tid = threadIdx.x;
    int h = tid & 63;
    int slot = tid >> 6;
    float w[HDIM];
    #pragma unroll
    for (int d = 0; d < HDIM; ++d)
        w[d] = BF ? __bfloat162float(((const bf16*)W)[d * HDIM + h])
                  : ((const float*)W)[d * HDIM + h];
    float bias = BF ? __bfloat162float(((const bf16*)b)[h]) : ((const float*)b)[h];
    int base = blockIdx.x * 32;
    #pragma unroll
    for (int nn = 0; nn < 8; ++nn) {
        int node = base + nn * 4 + slot;
        int nc = node < N_NODES ? node : N_NODES - 1;
        const float4* f4 = (const float4*)(feat + (size_t)nc * HDIM);
        float a0 = bias, a1 = 0.f, a2 = 0.f, a3 = 0.f;
        {
            float4 f0 = f4[0], f1 = f4[1], f2 = f4[2], f3 = f4[3];
            float4 f5 = f4[4], f6 = f4[5], f7 = f4[6], f8 = f4[7];
            FMA4(a0, f0, 0); FMA4(a1, f1, 1); FMA4(a2, f2, 2); FMA4(a3, f3, 3);
            FMA4(a0, f5, 4); FMA4(a1, f6, 5); FMA4(a2, f7, 6); FMA4(a3, f8, 7);
        }
        {
            float4 g0 = f4[8],  g1 = f4[9],  g2 = f4[10], g3 = f4[11];
            float4 g5 = f4[12], g6 = f4[13], g7 = f4[14], g8 = f4[15];
            FMA4(a0, g0, 8);  FMA4(a1, g1, 9);  FMA4(a2, g2, 10); FMA4(a3, g3, 11);
            FMA4(a0, g5, 12); FMA4(a1, g6, 13); FMA4(a2, g7, 14); FMA4(a3, g8, 15);
        }
        if (node < N_NODES)
            out[(size_t)node * HDIM + h] = f2bf((a0 + a1) + (a2 + a3));
    }
}

// ---------------- fused GATv2 attention (R19: 8-lane subgroups) ------------
// Wave = 8 subgroups x 8 lanes; lane = g*8+c holds features 8c..8c+7 of its
// subgroup's edge (ushort8 16B gathers). Chunk = 16 edges (2 its x 8 edges).
// Single-pass bounded-score softmax in log2 domain (R18).
__global__ __launch_bounds__(256) void gat_row_kernel(
    const int* __restrict__ rowptr, const int* __restrict__ col_src,
    const unsigned short* __restrict__ xl, const unsigned short* __restrict__ xr,
    const void* ab, const void* af, const int* __restrict__ flag,
    float* __restrict__ hn, int init)
{
    int bf = flag[0];
    const void* att = bf ? ab : af;
    int wave = threadIdx.x >> 6;
    int lane = threadIdx.x & 63;
    int d = blockIdx.x * 4 + wave;
    if (d >= N_NODES) return;
    int rs = rowptr[d], re = rowptr[d + 1];

    int g = lane >> 3;     // subgroup 0..7 (edge slot)
    int c = lane & 7;      // feature octet index

    if (re <= rs) {
        if (g == 0 && init) {
            float4 z = make_float4(0.f, 0.f, 0.f, 0.f);
            float4* op = (float4*)(hn + (size_t)d * HDIM + 8u * c);
            op[0] = z; op[1] = z;
        }
        return;
    }

    const float LOG2E = 1.44269504088896340736f;
    float attv[8];
    #pragma unroll
    for (int k = 0; k < 8; ++k) attv[k] = ldf(att, 8 * c + k, bf) * LOG2E;
    ushort8v xr8 = *(const ushort8v*)(xr + (unsigned)d * HDIM + 8u * c);
    float xrv[8];
    #pragma unroll
    for (int k = 0; k < 8; ++k) xrv[k] = bf2f((unsigned short)xr8[k]);

    float acc[8] = {0.f, 0.f, 0.f, 0.f, 0.f, 0.f, 0.f, 0.f};
    float s = 0.f;

    for (int cs0 = rs; cs0 < re; cs0 += 16) {
        int ii = cs0 + (lane & 15);
        int srcv = (ii < re) ? col_src[ii] : 0;

        #pragma unroll
        for (int it = 0; it < 2; ++it) {
            int ei = cs0 + it * 8 + g;
            bool valid = ei < re;
            int src = __shfl(srcv, it * 8 + g, 64);
            float xv[8];
            if (valid) {
                unsigned off = (unsigned)src * HDIM + 8u * c;
                ushort8v u8 = *(const ushort8v*)(xl + off);
                #pragma unroll
                for (int k = 0; k < 8; ++k) xv[k] = bf2f((unsigned short)u8[k]);
            } else {
                #pragma unroll
                for (int k = 0; k < 8; ++k) xv[k] = 0.f;
            }
            float t = 0.f;
            #pragma unroll
            for (int k = 0; k < 8; ++k) {
                float v = xv[k] + xrv[k];
                float l = fmaf(0.4f, fabsf(v), 0.6f * v);   // leaky(0.2)
                t = fmaf(attv[k], l, t);
            }
            t += __shfl_xor(t, 1, 64);
            t += __shfl_xor(t, 2, 64);
            t += __shfl_xor(t, 4, 64);
            float w = valid ? exp2f(t) : 0.f;
            s += w;
            #pragma unroll
            for (int k = 0; k < 8; ++k) acc[k] = fmaf(w, xv[k], acc[k]);
        }
    }
    #pragma unroll
    for (int k = 0; k < 8; ++k) {
        acc[k] += __shfl_xor(acc[k], 8, 64);
        acc[k] += __shfl_xor(acc[k], 16, 64);
        acc[k] += __shfl_xor(acc[k], 32, 64);
    }
    s += __shfl_xor(s, 8, 64);
    s += __shfl_xor(s, 16, 64);
    s += __shfl_xor(s, 32, 64);

    if (g == 0) {
        float inv = 1.f / (s + 1e-16f);
        float4* op = (float4*)(hn + (size_t)d * HDIM + 8u * c);
        float4 v0 = make_float4(acc[0] * inv, acc[1] * inv, acc[2] * inv, acc[3] * inv);
        float4 v1 = make_float4(acc[4] * inv, acc[5] * inv, acc[6] * inv, acc[7] * inv);
        if (init) {
            op[0] = v0; op[1] = v1;
        } else {
            float4 o0 = op[0], o1 = op[1];
            op[0] = make_float4(o0.x + v0.x, o0.y + v0.y, o0.z + v0.z, o0.w + v0.w);
            op[1] = make_float4(o1.x + v1.x, o1.y + v1.y, o1.z + v1.z, o1.w + v1.w);
        }
    }
}

// ---------------- epilogue ----------------

__global__ void bsum_kernel(const void* __restrict__ bias, const int* __restrict__ flag,
                            float* __restrict__ bsum)
{
    int bf = flag[0];
    int idx = threadIdx.x;  // 192 = 3*64
    if (idx >= 192) return;
    int nt = idx >> 6, h = idx & 63;
    float v;
    if (nt == 0)      v = ldf(bias, 0*64+h, bf) + ldf(bias, 1*64+h, bf) + ldf(bias, 4*64+h, bf);
    else if (nt == 1) v = ldf(bias, 2*64+h, bf) + ldf(bias, 5*64+h, bf);
    else              v = ldf(bias, 3*64+h, bf) + ldf(bias, 6*64+h, bf);
    bsum[idx] = v;
}

__global__ __launch_bounds__(256) void relu_kernel(
    const float* __restrict__ hn, const float* __restrict__ bsum,
    float* __restrict__ h, unsigned short* __restrict__ fbout)
{
    size_t idx = (size_t)blockIdx.x * 256 + threadIdx.x;
    if (idx >= (size_t)3 * N_NODES * HDIM) return;
    int nt = (int)(idx / ((size_t)N_NODES * HDIM));
    int hh = (int)(idx & 63);
    float v = hn[idx] + bsum[nt * 64 + hh];
    v = v > 0.f ? v : 0.f;
    h[idx] = v;
    if (fbout) fbout[idx] = f2bf(v);
}

__global__ __launch_bounds__(256) void head_kernel(
    const float* __restrict__ h0, const void* __restrict__ Wout,
    const void* __restrict__ bout, const int* __restrict__ flag,
    void* __restrict__ out)
{
    __shared__ float sW[64 * 4];
    __shared__ float sb[4];
    int bf = flag[0];
    int tid = threadIdx.x;
    sW[tid] = ldf(Wout, tid, bf);
    if (tid < 4) sb[tid] = ldf(bout, tid, bf);
    __syncthreads();
    int i = blockIdx.x * 256 + tid;
    if (i >= N_NODES) return;
    float l0 = sb[0], l1 = sb[1], l2 = sb[2], l3 = sb[3];
    const float4* p = (const float4*)(h0 + (size_t)i * HDIM);
    #pragma unroll
    for (int k = 0; k < 16; ++k) {
        float4 a = p[k];
        int d = 4 * k;
        l0 += a.x * sW[d*4+0] + a.y * sW[(d+1)*4+0] + a.z * sW[(d+2)*4+0] + a.w * sW[(d+3)*4+0];
        l1 += a.x * sW[d*4+1] + a.y * sW[(d+1)*4+1] + a.z * sW[(d+2)*4+1] + a.w * sW[(d+3)*4+1];
        l2 += a.x * sW[d*4+2] + a.y * sW[(d+1)*4+2] + a.z * sW[(d+2)*4+2] + a.w * sW[(d+3)*4+2];
        l3 += a.x * sW[d*4+3] + a.y * sW[(d+1)*4+3] + a.z * sW[(d+2)*4+3] + a.w * sW[(d+3)*4+3];
    }
    float m = fmaxf(fmaxf(l0, l1), fmaxf(l2, l3));
    float e0 = __expf(l0 - m), e1 = __expf(l1 - m), e2 = __expf(l2 - m), e3 = __expf(l3 - m);
    float inv = 1.f / (e0 + e1 + e2 + e3);
    if (bf) {
        bf16* o = (bf16*)out;
        o[(size_t)4*i + 0] = __float2bfloat16(e0 * inv);
        o[(size_t)4*i + 1] = __float2bfloat16(e1 * inv);
        o[(size_t)4*i + 2] = __float2bfloat16(e2 * inv);
        o[(size_t)4*i + 3] = __float2bfloat16(e3 * inv);
    } else {
        float* o = (float*)out;
        o[(size_t)4*i + 0] = e0 * inv;
        o[(size_t)4*i + 1] = e1 * inv;
        o[(size_t)4*i + 2] = e2 * inv;
        o[(size_t)4*i + 3] = e3 * inv;
    }
}

struct P2 { const void* b; const void* f; };
static inline P2 off2(const void* base, size_t elem) {
    P2 r;
    r.b = (const void*)((const bf16*)base + elem);
    r.f = (const void*)((const float*)base + elem);
    return r;
}

extern "C" void kernel_launch(void* const* d_in, const int* in_sizes, int n_in,
                              void* d_out, int out_size, void* d_ws, size_t ws_size,
                              hipStream_t stream)
{
    const void* x     = d_in[0];
    const int*  edges = (const int*)d_in[1];
    const void* Wl0 = d_in[2];
    const void* Wr0 = d_in[3];
    const void* bl0 = d_in[4];
    const void* br0 = d_in[5];
    const void* att0 = d_in[6];
    const void* bias0 = d_in[7];
    const void* Wl1 = d_in[8];
    const void* Wr1 = d_in[9];
    const void* bl1 = d_in[10];
    const void* br1 = d_in[11];
    const void* att1 = d_in[12];
    const void* bias1 = d_in[13];
    const void* Wout = d_in[14];
    const void* bout = d_in[15];

    const int SRCt[7] = {0, 1, 1, 1, 2, 2, 2};
    const int DSTt[7] = {0, 0, 1, 2, 0, 1, 2};

    // ---- workspace layout ----
    float* h3  = (float*)d_ws;                                  // 3*N*H
    float* hn3 = h3 + (size_t)3 * N_NODES * HDIM;               // 3*N*H (38.4 MB)
    unsigned short* xl = (unsigned short*)(hn3 + (size_t)3 * N_NODES * HDIM); // N*H bf16
    unsigned short* xr = xl + (size_t)N_NODES * HDIM;           // N*H bf16
    char* tail = (char*)(xl + (size_t)2 * N_NODES * HDIM) + (size_t)2 * N_NODES * HDIM * 2;

    size_t fixed = (size_t)tail - (size_t)d_ws;
    size_t base_need = fixed + ((size_t)NROWS + 1) * 4 + (size_t)7 * NEDGE * 4
                     + (NCB + 1) * 4 + 2 * 256 * 4 + 192 * 4 + 4
                     + 2 * (size_t)N_NODES * 4 + 512;
    size_t mfma_extra = (size_t)3 * N_NODES * HDIM * 2
                      + (size_t)7 * 2 * 64 * HDIM * 2
                      + (size_t)7 * 2 * 64 * DIN * 2 + 512;
    bool full = ws_size >= base_need;
    bool mfma_ok = ws_size >= base_need + mfma_extra;
    int NT = full ? 7 : 1;

    int* P        = (int*)tail;                                 // NT*N+1
    int* col_src  = P + ((size_t)NT * N_NODES + 1);             // NT*E
    int* cbase    = col_src + (size_t)NT * NEDGE;               // NCB+1
    int* bsums    = cbase + (NCB + 1);                          // 256
    int* boffs    = bsums + 256;                                // 256
    float* bsum   = (float*)(boffs + 256);                      // 192
    int* flag     = (int*)(bsum + 192);                         // 1
    int* cnt      = flag + 1;                                   // N (fallback)
    int* cursor   = cnt + N_NODES;                              // N (fallback)
    unsigned short* fb  = (unsigned short*)(((size_t)(cursor + N_NODES) + 255) & ~(size_t)255);
    unsigned short* wt1 = fb + (size_t)3 * N_NODES * HDIM;
    unsigned short* wt0 = wt1 + (size_t)7 * 2 * 64 * HDIM;

    unsigned* buf = (unsigned*)hn3;                             // 7E (22.4 MB)
    int* cnt2d    = (int*)(buf + (size_t)7 * NEDGE);            // NCB*NBLK1 (1.87 MB)

    dim3 blk(256);
    int gLin  = (N_NODES + 31) / 32;
    int gGemm = (N_NODES + 63) / 64;
    int gRow  = (N_NODES + 3) / 4;
    int gRelu = (int)(((size_t)3 * N_NODES * HDIM + 255) / 256);
    int gHead = (N_NODES + 255) / 256;

    detect_kernel<<<1, 256, 0, stream>>>((const unsigned short*)x, flag);

    if (full) {
        k1_count_kernel<<<NBLK1, 1024, 0, stream>>>(edges, cnt2d);
        k2_colscan_kernel<<<NCB, blk, 0, stream>>>(cnt2d, cbase);
        k3_cscan_kernel<<<1, blk, 0, stream>>>(cbase, P);
        part1_kernel<<<NBLK1, 1024, 0, stream>>>(edges, cnt2d, cbase, buf);
        part2_kernel<<<NCB, blk, 0, stream>>>(buf, cbase, P, col_src);
    }

    for (int layer = 0; layer < 2; ++layer) {
        const void* Wl = layer ? Wl1 : Wl0;
        const void* Wr = layer ? Wr1 : Wr0;
        const void* bl = layer ? bl1 : bl0;
        const void* br = layer ? br1 : br0;
        const void* at = layer ? att1 : att0;
        const void* bi = layer ? bias1 : bias0;
        int K = layer ? HDIM : DIN;

        bsum_kernel<<<1, 192, 0, stream>>>(bi, flag, bsum);

        if (mfma_ok) {
            if (layer == 0) {
                size_t nfeat = (size_t)3 * N_NODES * DIN;
                cvt_feat_kernel<<<(int)((nfeat / 4 + 255) / 256), blk, 0, stream>>>(
                    x, -1, flag, fb, nfeat);
            }
            unsigned short* wt = layer ? wt1 : wt0;
            cvt_w_kernel<<<dim3(7, 2), blk, 0, stream>>>(
                off2(Wl, 0).b, off2(Wl, 0).f, off2(Wr, 0).b, off2(Wr, 0).f, flag, wt, K);
        }

        for (int t = 0; t < 7; ++t) {
            const int* rp;
            const int* cs;
            if (full) {
                rp = P + (size_t)t * N_NODES;
                cs = col_src;
            } else {
                const int* et = edges + (size_t)t * 2 * NEDGE;
                int n = N_NODES;
                int nb = (n + 2047) / 2048;
                int gE1 = (NEDGE + 255) / 256;
                hipMemsetAsync(cnt, 0, (size_t)n * sizeof(int), stream);
                hist_kernel<<<gE1, blk, 0, stream>>>(et, cnt, 1);
                scanA_kernel<<<nb, blk, 0, stream>>>(cnt, bsums, n);
                scanB_kernel<<<1, blk, 0, stream>>>(bsums, boffs, nb, P, n);
                scanC_kernel<<<nb, blk, 0, stream>>>(cnt, boffs, P, cursor, n);
                scatter1_kernel<<<gE1, blk, 0, stream>>>(et, cursor, col_src);
                rp = P;
                cs = col_src;
            }

            P2 bL = off2(bl, (size_t)t * HDIM);
            P2 bR = off2(br, (size_t)t * HDIM);
            if (mfma_ok) {
                unsigned short* wt = (layer ? wt1 : wt0) + (size_t)t * 2 * 64 * K;
                if (layer == 0)
                    gemm_lin_t<DIN><<<dim3(gGemm, 2), blk, 0, stream>>>(
                        fb, SRCt[t], DSTt[t], wt, bL.b, bL.f, bR.b, bR.f, flag, xl, xr);
                else
                    gemm_lin_t<HDIM><<<dim3(gGemm, 2), blk, 0, stream>>>(
                        fb, SRCt[t], DSTt[t], wt, bL.b, bL.f, bR.b, bR.f, flag, xl, xr);
            } else if (layer == 0) {
                P2 fs = off2(x, (size_t)SRCt[t] * N_NODES * DIN);
                P2 fd = off2(x, (size_t)DSTt[t] * N_NODES * DIN);
                P2 wl = off2(Wl, (size_t)t * DIN * HDIM);
                P2 wr = off2(Wr, (size_t)t * DIN * HDIM);
                lin_d32_t<0><<<dim3(gLin, 2), blk, 0, stream>>>(
                    fs.b, fs.f, fd.b, fd.f, wl.b, wl.f, wr.b, wr.f,
                    bL.b, bL.f, bR.b, bR.f, flag, xl, xr);
                lin_d32_t<1><<<dim3(gLin, 2), blk, 0, stream>>>(
                    fs.b, fs.f, fd.b, fd.f, wl.b, wl.f, wr.b, wr.f,
                    bL.b, bL.f, bR.b, bR.f, flag, xl, xr);
            } else {
                P2 wl = off2(Wl, (size_t)t * HDIM * HDIM);
                P2 wr = off2(Wr, (size_t)t * HDIM * HDIM);
                const float* fL = h3 + (size_t)SRCt[t] * N_NODES * HDIM;
                const float* fR = h3 + (size_t)DSTt[t] * N_NODES * HDIM;
                lin_d64_t<0><<<dim3(gLin, 2), blk, 0, stream>>>(
                    fL, fR, wl.b, wl.f, wr.b, wr.f, bL.b, bL.f, bR.b, bR.f, flag, xl, xr);
                lin_d64_t<1><<<dim3(gLin, 2), blk, 0, stream>>>(
                    fL, fR, wl.b, wl.f, wr.b, wr.f, bL.b, bL.f, bR.b, bR.f, flag, xl, xr);
            }

            int init = (t == 0 || t == 2 || t == 3) ? 1 : 0;
            P2 a2 = off2(at, (size_t)t * HDIM);
            gat_row_kernel<<<gRow, blk, 0, stream>>>(rp, cs, xl, xr,
                                                     a2.b, a2.f, flag,
                                                     hn3 + (size_t)DSTt[t] * N_NODES * HDIM,
                                                     init);
        }
        relu_kernel<<<gRelu, blk, 0, stream>>>(hn3, bsum, h3,
                                               (mfma_ok && layer == 0) ? fb : (unsigned short*)nullptr);
    }

    head_kernel<<<gHead, blk, 0, stream>>>(h3, Wout, bout, flag, d_out);
}

// Round 20
// 864.142 us; speedup vs baseline: 1.0784x; 1.0784x over previous
//
#include <hip/hip_runtime.h>
#include <hip/hip_bf16.h>

// HeteroGATv2: 3 node types x 50000 nodes, 7 edge types x 800000 edges,
// 2 GATv2 layers (H=64), softmax head (4 classes) on node type 0.
//
// R20: REVERT gat_row to the R18 shape (16-lane subgroups x float4,
// single-pass log2-domain bounded-score softmax). R19's 8-lane re-geometry
// regressed (44.5 -> 49.7us): per-lane dependency chains doubled (8-deep
// score FMA chain, 8-wide convert/acc arrays) and VALUBusy fell 57->48% --
// issue-count arithmetic ignored chain depth. This file = R18 exactly.

#define N_NODES 50000
#define NEDGE   800000
#define HDIM    64
#define DIN     32
#define NROWS   (7 * N_NODES)          // 350000 global rows (type-major)
#define CROWS   512                    // rows per coarse bucket
#define NCB     684                    // ceil(NROWS/CROWS)
#define TILE1   8192                   // edges per k1/pass1 block
#define NBLK1   684                    // ceil(7*NEDGE/TILE1)
#define K2IT    3                      // ceil(NBLK1/256)
#define SCAP    10240                  // part2 LDS staging cap

typedef __hip_bfloat16 bf16;
typedef short short8v __attribute__((ext_vector_type(8)));
typedef float f32x4 __attribute__((ext_vector_type(4)));

__device__ __forceinline__ float ldf(const void* p, size_t i, int bf) {
    return bf ? __bfloat162float(((const bf16*)p)[i]) : ((const float*)p)[i];
}
__device__ __forceinline__ unsigned short f2bf(float f) {
    bf16 b = __float2bfloat16(f);
    return *(unsigned short*)&b;
}
__device__ __forceinline__ float bf2f(unsigned short u) {
    return __uint_as_float((unsigned)u << 16);
}

// flag[0] = 1 if x is bf16, 0 if f32.
__global__ void detect_kernel(const unsigned short* __restrict__ x, int* __restrict__ flag)
{
    __shared__ int sbad[256];
    int bad = 0;
    for (int i = threadIdx.x; i < 4096; i += 256) {
        unsigned short u = x[i];
        int ex = (u >> 7) & 0xff;
        bool zero = (u & 0x7fffu) == 0;
        if (!zero && (ex < 80 || ex > 140)) bad++;
    }
    sbad[threadIdx.x] = bad;
    __syncthreads();
    for (int s = 128; s > 0; s >>= 1) {
        if (threadIdx.x < s) sbad[threadIdx.x] += sbad[threadIdx.x + s];
        __syncthreads();
    }
    if (threadIdx.x == 0) flag[0] = (sbad[0] < 64) ? 1 : 0;
}

// ---------------- radix-partition CSR build (full path) ----------------

__global__ __launch_bounds__(1024) void k1_count_kernel(const int* __restrict__ edges,
                                                        int* __restrict__ cnt2d)
{
    __shared__ int lcount[NCB];
    for (int i = threadIdx.x; i < NCB; i += 1024) lcount[i] = 0;
    __syncthreads();
    int g0 = blockIdx.x * TILE1;
    #pragma unroll
    for (int k = 0; k < TILE1 / 1024; ++k) {
        int g = g0 + k * 1024 + threadIdx.x;
        if (g < 7 * NEDGE) {
            int t = g / NEDGE, i = g - t * NEDGE;
            int d = edges[(size_t)t * 2 * NEDGE + NEDGE + i];
            int r = t * N_NODES + d;
            atomicAdd(&lcount[r >> 9], 1);
        }
    }
    __syncthreads();
    for (int i = threadIdx.x; i < NCB; i += 1024)
        cnt2d[(size_t)i * NBLK1 + blockIdx.x] = lcount[i];
}

__global__ __launch_bounds__(256) void k2_colscan_kernel(int* __restrict__ cnt2d,
                                                         int* __restrict__ cbase)
{
    __shared__ int sv[256];
    int t = threadIdx.x;
    int* col = cnt2d + (size_t)blockIdx.x * NBLK1;
    int a[K2IT]; int s = 0;
    #pragma unroll
    for (int k = 0; k < K2IT; ++k) {
        int i = t * K2IT + k;
        a[k] = (i < NBLK1) ? col[i] : 0;
        s += a[k];
    }
    sv[t] = s; __syncthreads();
    for (int off = 1; off < 256; off <<= 1) {
        int v = (t >= off) ? sv[t - off] : 0; __syncthreads();
        sv[t] += v; __syncthreads();
    }
    int excl = sv[t] - s;
    #pragma unroll
    for (int k = 0; k < K2IT; ++k) {
        int i = t * K2IT + k;
        if (i < NBLK1) { col[i] = excl; excl += a[k]; }
    }
    if (t == 255) cbase[blockIdx.x] = sv[255];
}

__global__ __launch_bounds__(256) void k3_cscan_kernel(int* __restrict__ cbase,
                                                       int* __restrict__ P)
{
    __shared__ int sv[256];
    int t = threadIdx.x;
    int a[3]; int s = 0;
    #pragma unroll
    for (int k = 0; k < 3; ++k) {
        int i = t * 3 + k;
        a[k] = (i < NCB) ? cbase[i] : 0;
        s += a[k];
    }
    sv[t] = s; __syncthreads();
    for (int off = 1; off < 256; off <<= 1) {
        int v = (t >= off) ? sv[t - off] : 0; __syncthreads();
        sv[t] += v; __syncthreads();
    }
    int excl = sv[t] - s;
    #pragma unroll
    for (int k = 0; k < 3; ++k) {
        int i = t * 3 + k;
        if (i < NCB) { cbase[i] = excl; excl += a[k]; }
    }
    if (t == 255) { cbase[NCB] = sv[255]; P[NROWS] = sv[255]; }
}

__global__ __launch_bounds__(1024) void part1_kernel(const int* __restrict__ edges,
                                                     const int* __restrict__ cnt2d,
                                                     const int* __restrict__ cbase,
                                                     unsigned* __restrict__ buf)
{
    __shared__ int lcur[NCB];
    for (int i = threadIdx.x; i < NCB; i += 1024)
        lcur[i] = cbase[i] + cnt2d[(size_t)i * NBLK1 + blockIdx.x];
    __syncthreads();
    int g0 = blockIdx.x * TILE1;
    #pragma unroll
    for (int k = 0; k < TILE1 / 1024; ++k) {
        int g = g0 + k * 1024 + threadIdx.x;
        if (g < 7 * NEDGE) {
            int t = g / NEDGE, i = g - t * NEDGE;
            int s = edges[(size_t)t * 2 * NEDGE + i];
            int d = edges[(size_t)t * 2 * NEDGE + NEDGE + i];
            int r = t * N_NODES + d;
            int pos = atomicAdd(&lcur[r >> 9], 1);
            buf[pos] = ((unsigned)(r & 511) << 16) | (unsigned)s;
        }
    }
}

__global__ __launch_bounds__(256) void part2_kernel(const unsigned* __restrict__ buf,
                                                    const int* __restrict__ cbase,
                                                    int* __restrict__ P,
                                                    int* __restrict__ col_src)
{
    __shared__ int fcnt[CROWS];
    __shared__ int fpos[CROWS];
    __shared__ int sv[256];
    __shared__ int stage[SCAP];
    int b = blockIdx.x;
    int t = threadIdx.x;
    int start = cbase[b], end = cbase[b + 1];
    int cnt = end - start;
    fcnt[2 * t] = 0; fcnt[2 * t + 1] = 0;
    __syncthreads();
    for (int i = start + t; i < end; i += 256)
        atomicAdd(&fcnt[buf[i] >> 16], 1);
    __syncthreads();
    int a0 = fcnt[2 * t], a1 = fcnt[2 * t + 1];
    int s = a0 + a1;
    sv[t] = s; __syncthreads();
    for (int off = 1; off < 256; off <<= 1) {
        int v = (t >= off) ? sv[t - off] : 0; __syncthreads();
        sv[t] += v; __syncthreads();
    }
    int excl = sv[t] - s;
    fpos[2 * t] = excl; fpos[2 * t + 1] = excl + a0;
    int r0 = b * CROWS;
    int rows_in = NROWS - r0; if (rows_in > CROWS) rows_in = CROWS;
    if (2 * t < rows_in)     P[r0 + 2 * t]     = start + excl;
    if (2 * t + 1 < rows_in) P[r0 + 2 * t + 1] = start + excl + a0;
    __syncthreads();
    if (cnt <= SCAP) {
        for (int i = start + t; i < end; i += 256) {
            unsigned v = buf[i];
            int pos = atomicAdd(&fpos[v >> 16], 1);
            stage[pos] = (int)(v & 0xffffu);
        }
        __syncthreads();
        for (int i = t; i < cnt; i += 256)
            col_src[start + i] = stage[i];
    } else {
        for (int i = start + t; i < end; i += 256) {
            unsigned v = buf[i];
            int pos = start + atomicAdd(&fpos[v >> 16], 1);
            col_src[pos] = (int)(v & 0xffffu);
        }
    }
}

// ---------------- fallback CSR build (ws-limited) ----------------

__global__ __launch_bounds__(256) void hist_kernel(const int* __restrict__ edges,
                                                   int* __restrict__ cnt, int ntypes)
{
    int g = blockIdx.x * 256 + threadIdx.x;
    if (g >= ntypes * NEDGE) return;
    int t = g / NEDGE, i = g - t * NEDGE;
    int d = edges[(size_t)t * 2 * NEDGE + NEDGE + i];
    atomicAdd(&cnt[t * N_NODES + d], 1);
}

__global__ __launch_bounds__(256) void scanA_kernel(const int* __restrict__ cnt,
                                                    int* __restrict__ bsums, int n)
{
    __shared__ int lds[256];
    int tid = threadIdx.x;
    int base = blockIdx.x * 2048 + tid * 8;
    int s = 0;
    #pragma unroll
    for (int k = 0; k < 8; ++k) { int i = base + k; if (i < n) s += cnt[i]; }
    lds[tid] = s;
    __syncthreads();
    for (int o = 128; o > 0; o >>= 1) {
        if (tid < o) lds[tid] += lds[tid + o];
        __syncthreads();
    }
    if (tid == 0) bsums[blockIdx.x] = lds[0];
}

__global__ __launch_bounds__(256) void scanB_kernel(const int* __restrict__ bsums,
                                                    int* __restrict__ boffs, int nb,
                                                    int* __restrict__ P, int n)
{
    __shared__ int lds[256];
    int tid = threadIdx.x;
    int v = (tid < nb) ? bsums[tid] : 0;
    lds[tid] = v;
    __syncthreads();
    for (int off = 1; off < 256; off <<= 1) {
        int t2 = (tid >= off) ? lds[tid - off] : 0;
        __syncthreads();
        lds[tid] += t2;
        __syncthreads();
    }
    if (tid < nb) boffs[tid] = lds[tid] - v;
    if (tid == 255) P[n] = lds[255];
}

__global__ __launch_bounds__(256) void scanC_kernel(const int* __restrict__ cnt,
                                                    const int* __restrict__ boffs,
                                                    int* __restrict__ P,
                                                    int* __restrict__ cursor, int n)
{
    __shared__ int lds[256];
    int tid = threadIdx.x;
    int base = blockIdx.x * 2048 + tid * 8;
    int v[8];
    int s = 0;
    #pragma unroll
    for (int k = 0; k < 8; ++k) {
        int i = base + k;
        int c = (i < n) ? cnt[i] : 0;
        v[k] = s;
        s += c;
    }
    lds[tid] = s;
    __syncthreads();
    for (int off = 1; off < 256; off <<= 1) {
        int t2 = (tid >= off) ? lds[tid - off] : 0;
        __syncthreads();
        lds[tid] += t2;
        __syncthreads();
    }
    int off0 = boffs[blockIdx.x] + (lds[tid] - s);
    #pragma unroll
    for (int k = 0; k < 8; ++k) {
        int i = base + k;
        if (i < n) { int val = off0 + v[k]; P[i] = val; cursor[i] = val; }
    }
}

__global__ __launch_bounds__(256) void scatter1_kernel(const int* __restrict__ et,
                                                       int* __restrict__ cursor,
                                                       int* __restrict__ col_src)
{
    int i = blockIdx.x * 256 + threadIdx.x;
    if (i >= NEDGE) return;
    int s = et[i], d = et[NEDGE + i];
    int pos = atomicAdd(&cursor[d], 1);
    col_src[pos] = s;
}

// ---------------- bf16 converts ----------------

__global__ __launch_bounds__(256) void cvt_feat_kernel(const void* __restrict__ in,
                                                       int bfmode, const int* __restrict__ flag,
                                                       unsigned short* __restrict__ out, size_t n)
{
    int bf = bfmode < 0 ? flag[0] : bfmode;
    size_t i = ((size_t)blockIdx.x * 256 + threadIdx.x) * 4;
    if (i + 3 < n) {
        ushort4 o;
        o.x = f2bf(ldf(in, i + 0, bf));
        o.y = f2bf(ldf(in, i + 1, bf));
        o.z = f2bf(ldf(in, i + 2, bf));
        o.w = f2bf(ldf(in, i + 3, bf));
        *(ushort4*)(out + i) = o;
    } else {
        for (size_t j = i; j < n; ++j) out[j] = f2bf(ldf(in, j, bf));
    }
}

__global__ void cvt_w_kernel(const void* __restrict__ WlB, const void* __restrict__ WlF,
                             const void* __restrict__ WrB, const void* __restrict__ WrF,
                             const int* __restrict__ flag, unsigned short* __restrict__ wt, int K)
{
    int bf = flag[0];
    int t = blockIdx.x, side = blockIdx.y;
    const void* W = side ? (bf ? WrB : WrF) : (bf ? WlB : WlF);
    unsigned short* o = wt + ((size_t)t * 2 + side) * 64 * K;
    for (int idx = threadIdx.x; idx < 64 * K; idx += 256) {
        int n = idx / K, k = idx - n * K;
        o[idx] = f2bf(ldf(W, (size_t)t * K * 64 + (size_t)k * 64 + n, bf));
    }
}

// ---------------- MFMA lin GEMM: [50000 x K] @ [K x 64] + bias -> bf16 ------
template<int K>
__global__ __launch_bounds__(256) void gemm_lin_t(
    const unsigned short* __restrict__ fb, int srcT, int dstT,
    const unsigned short* __restrict__ wt,
    const void* blB, const void* blF, const void* brB, const void* brF,
    const int* __restrict__ flag,
    unsigned short* __restrict__ xl, unsigned short* __restrict__ xr)
{
    int side = blockIdx.y;
    int bf = flag[0];
    const unsigned short* A = fb + (size_t)(side ? dstT : srcT) * N_NODES * K;
    const unsigned short* W = wt + (size_t)side * 64 * K;
    const void* bias = side ? (bf ? brB : brF) : (bf ? blB : blF);
    unsigned short* out = side ? xr : xl;

    int wave = threadIdx.x >> 6;
    int lane = threadIdx.x & 63;
    int m0 = blockIdx.x * 64 + wave * 16;
    if (m0 >= N_NODES) return;
    int lg = lane >> 4;
    int lr = lane & 15;

    short8v afrag[K / 32];
    #pragma unroll
    for (int ks = 0; ks < K / 32; ++ks)
        afrag[ks] = *(const short8v*)(A + (size_t)(m0 + lr) * K + ks * 32 + lg * 8);

    f32x4 acc0 = {0.f, 0.f, 0.f, 0.f};
    f32x4 acc1 = {0.f, 0.f, 0.f, 0.f};
    f32x4 acc2 = {0.f, 0.f, 0.f, 0.f};
    f32x4 acc3 = {0.f, 0.f, 0.f, 0.f};
    #pragma unroll
    for (int ks = 0; ks < K / 32; ++ks) {
        short8v b0 = *(const short8v*)(W + (size_t)(0 * 16 + lr) * K + ks * 32 + lg * 8);
        short8v b1 = *(const short8v*)(W + (size_t)(1 * 16 + lr) * K + ks * 32 + lg * 8);
        short8v b2 = *(const short8v*)(W + (size_t)(2 * 16 + lr) * K + ks * 32 + lg * 8);
        short8v b3 = *(const short8v*)(W + (size_t)(3 * 16 + lr) * K + ks * 32 + lg * 8);
        acc0 = __builtin_amdgcn_mfma_f32_16x16x32_bf16(afrag[ks], b0, acc0, 0, 0, 0);
        acc1 = __builtin_amdgcn_mfma_f32_16x16x32_bf16(afrag[ks], b1, acc1, 0, 0, 0);
        acc2 = __builtin_amdgcn_mfma_f32_16x16x32_bf16(afrag[ks], b2, acc2, 0, 0, 0);
        acc3 = __builtin_amdgcn_mfma_f32_16x16x32_bf16(afrag[ks], b3, acc3, 0, 0, 0);
    }
    #pragma unroll
    for (int nt = 0; nt < 4; ++nt) {
        f32x4 a = nt == 0 ? acc0 : nt == 1 ? acc1 : nt == 2 ? acc2 : acc3;
        int n = nt * 16 + lr;
        float bb = ldf(bias, n, bf);
        #pragma unroll
        for (int r = 0; r < 4; ++r)
            out[(size_t)(m0 + lg * 4 + r) * HDIM + n] = f2bf(a[r] + bb);
    }
}

// ---------------- fallback linear transforms (write bf16) ----------------

#define FMA4(acc, f, i) acc += (f).x * w[4*(i)] + (f).y * w[4*(i)+1] \
                             + (f).z * w[4*(i)+2] + (f).w * w[4*(i)+3]
#define FMAI(acc, u, i) acc += __uint_as_float(((unsigned)(u)) << 16) * w[2*(i)] \
                             + __uint_as_float(((unsigned)(u)) & 0xffff0000u) * w[2*(i)+1]

template<int BF>
__global__ __launch_bounds__(256) void lin_d32_t(
    const void* fLb, const void* fLf, const void* fRb, const void* fRf,
    const void* wLb, const void* wLf, const void* wRb, const void* wRf,
    const void* bLb, const void* bLf, const void* bRb, const void* bRf,
    const int* __restrict__ flag,
    unsigned short* __restrict__ xl, unsigned short* __restrict__ xr)
{
    if (flag[0] != BF) return;
    int side = blockIdx.y;
    const void* W    = side ? (BF ? wRb : wRf) : (BF ? wLb : wLf);
    const void* b    = side ? (BF ? bRb : bRf) : (BF ? bLb : bLf);
    const void* feat = side ? (BF ? fRb : fRf) : (BF ? fLb : fLf);
    unsigned short* out = side ? xr : xl;
    int tid = threadIdx.x;
    int h = tid & 63;
    int slot = tid >> 6;
    float w[DIN];
    #pragma unroll
    for (int d = 0; d < DIN; ++d)
        w[d] = BF ? __bfloat162float(((const bf16*)W)[d * HDIM + h])
                  : ((const float*)W)[d * HDIM + h];
    float bias = BF ? __bfloat162float(((const bf16*)b)[h]) : ((const float*)b)[h];
    int base = blockIdx.x * 32;
    #pragma unroll
    for (int nn = 0; nn < 8; ++nn) {
        int node = base + nn * 4 + slot;
        int nc = node < N_NODES ? node : N_NODES - 1;
        float a0 = bias, a1 = 0.f, a2 = 0.f, a3 = 0.f;
        if (BF) {
            const int4* fp = (const int4*)((const bf16*)feat + (size_t)nc * DIN);
            int4 q0 = fp[0], q1 = fp[1], q2 = fp[2], q3 = fp[3];
            FMAI(a0, q0.x, 0);  FMAI(a1, q0.y, 1);  FMAI(a2, q0.z, 2);  FMAI(a3, q0.w, 3);
            FMAI(a0, q1.x, 4);  FMAI(a1, q1.y, 5);  FMAI(a2, q1.z, 6);  FMAI(a3, q1.w, 7);
            FMAI(a0, q2.x, 8);  FMAI(a1, q2.y, 9);  FMAI(a2, q2.z, 10); FMAI(a3, q2.w, 11);
            FMAI(a0, q3.x, 12); FMAI(a1, q3.y, 13); FMAI(a2, q3.z, 14); FMAI(a3, q3.w, 15);
        } else {
            const float4* f4 = (const float4*)((const float*)feat + (size_t)nc * DIN);
            float4 f0 = f4[0], f1 = f4[1], f2 = f4[2], f3 = f4[3];
            float4 f5 = f4[4], f6 = f4[5], f7 = f4[6], f8 = f4[7];
            FMA4(a0, f0, 0); FMA4(a1, f1, 1); FMA4(a2, f2, 2); FMA4(a3, f3, 3);
            FMA4(a0, f5, 4); FMA4(a1, f6, 5); FMA4(a2, f7, 6); FMA4(a3, f8, 7);
        }
        if (node < N_NODES)
            out[(size_t)node * HDIM + h] = f2bf((a0 + a1) + (a2 + a3));
    }
}

template<int BF>
__global__ __launch_bounds__(256) void lin_d64_t(
    const float* __restrict__ fL, const float* __restrict__ fR,
    const void* wLb, const void* wLf, const void* wRb, const void* wRf,
    const void* bLb, const void* bLf, const void* bRb, const void* bRf,
    const int* __restrict__ flag,
    unsigned short* __restrict__ xl, unsigned short* __restrict__ xr)
{
    if (flag[0] != BF) return;
    int side = blockIdx.y;
    const void* W = side ? (BF ? wRb : wRf) : (BF ? wLb : wLf);
    const void* b = side ? (BF ? bRb : bRf) : (BF ? bLb : bLf);
    const float* feat = side ? fR : fL;
    unsigned short* out = side ? xr : xl;
    int tid = threadIdx.x;
    int h = tid & 63;
    int slot = tid >> 6;
    float w[HDIM];
    #pragma unroll
    for (int d = 0; d < HDIM; ++d)
        w[d] = BF ? __bfloat162float(((const bf16*)W)[d * HDIM + h])
                  : ((const float*)W)[d * HDIM + h];
    float bias = BF ? __bfloat162float(((const bf16*)b)[h]) : ((const float*)b)[h];
    int base = blockIdx.x * 32;
    #pragma unroll
    for (int nn = 0; nn < 8; ++nn) {
        int node = base + nn * 4 + slot;
        int nc = node < N_NODES ? node : N_NODES - 1;
        const float4* f4 = (const float4*)(feat + (size_t)nc * HDIM);
        float a0 = bias, a1 = 0.f, a2 = 0.f, a3 = 0.f;
        {
            float4 f0 = f4[0], f1 = f4[1], f2 = f4[2], f3 = f4[3];
            float4 f5 = f4[4], f6 = f4[5], f7 = f4[6], f8 = f4[7];
            FMA4(a0, f0, 0); FMA4(a1, f1, 1); FMA4(a2, f2, 2); FMA4(a3, f3, 3);
            FMA4(a0, f5, 4); FMA4(a1, f6, 5); FMA4(a2, f7, 6); FMA4(a3, f8, 7);
        }
        {
            float4 g0 = f4[8],  g1 = f4[9],  g2 = f4[10], g3 = f4[11];
            float4 g5 = f4[12], g6 = f4[13], g7 = f4[14], g8 = f4[15];
            FMA4(a0, g0, 8);  FMA4(a1, g1, 9);  FMA4(a2, g2, 10); FMA4(a3, g3, 11);
            FMA4(a0, g5, 12); FMA4(a1, g6, 13); FMA4(a2, g7, 14); FMA4(a3, g8, 15);
        }
        if (node < N_NODES)
            out[(size_t)node * HDIM + h] = f2bf((a0 + a1) + (a2 + a3));
    }
}

// ---------------- fused GATv2 attention (R18 shape: single-pass, no max) ----
__global__ __launch_bounds__(256) void gat_row_kernel(
    const int* __restrict__ rowptr, const int* __restrict__ col_src,
    const unsigned short* __restrict__ xl, const unsigned short* __restrict__ xr,
    const void* ab, const void* af, const int* __restrict__ flag,
    float* __restrict__ hn, int init)
{
    int bf = flag[0];
    const void* att = bf ? ab : af;
    int wave = threadIdx.x >> 6;
    int lane = threadIdx.x & 63;
    int d = blockIdx.x * 4 + wave;
    if (d >= N_NODES) return;
    int rs = rowptr[d], re = rowptr[d + 1];

    int g = lane >> 4;
    int c = lane & 15;

    if (re <= rs) {
        if (init && g == 0)
            ((float4*)(hn + (size_t)d * HDIM))[c] = make_float4(0.f, 0.f, 0.f, 0.f);
        return;
    }

    const float LOG2E = 1.44269504088896340736f;
    float4 attv;
    attv.x = ldf(att, 4*c + 0, bf) * LOG2E;
    attv.y = ldf(att, 4*c + 1, bf) * LOG2E;
    attv.z = ldf(att, 4*c + 2, bf) * LOG2E;
    attv.w = ldf(att, 4*c + 3, bf) * LOG2E;
    ushort4 xr4 = *(const ushort4*)(xr + (unsigned)d * HDIM + 4u * c);
    float4 xrv = make_float4(bf2f(xr4.x), bf2f(xr4.y), bf2f(xr4.z), bf2f(xr4.w));

    float4 acc = make_float4(0.f, 0.f, 0.f, 0.f);
    float s = 0.f;

    for (int cs0 = rs; cs0 < re; cs0 += 16) {
        int ii = cs0 + c;
        int srcv = (ii < re) ? col_src[ii] : 0;

        #pragma unroll
        for (int it = 0; it < 4; ++it) {
            int ei = cs0 + it * 4 + g;
            bool valid = ei < re;
            int src = __shfl(srcv, it * 4 + g, 64);
            float4 xv = make_float4(0.f, 0.f, 0.f, 0.f);
            if (valid) {
                unsigned off = (unsigned)src * HDIM + 4u * c;
                ushort4 u4 = *(const ushort4*)(xl + off);
                xv = make_float4(bf2f(u4.x), bf2f(u4.y), bf2f(u4.z), bf2f(u4.w));
            }
            float v0 = xv.x + xrv.x, v1 = xv.y + xrv.y;
            float v2 = xv.z + xrv.z, v3 = xv.w + xrv.w;
            float l0 = fmaf(0.4f, fabsf(v0), 0.6f * v0);
            float l1 = fmaf(0.4f, fabsf(v1), 0.6f * v1);
            float l2 = fmaf(0.4f, fabsf(v2), 0.6f * v2);
            float l3 = fmaf(0.4f, fabsf(v3), 0.6f * v3);
            float t = fmaf(attv.w, l3, fmaf(attv.z, l2, fmaf(attv.y, l1, attv.x * l0)));
            t += __shfl_xor(t, 1, 64);
            t += __shfl_xor(t, 2, 64);
            t += __shfl_xor(t, 4, 64);
            t += __shfl_xor(t, 8, 64);
            float w = valid ? exp2f(t) : 0.f;
            s += w;
            acc.x = fmaf(w, xv.x, acc.x);
            acc.y = fmaf(w, xv.y, acc.y);
            acc.z = fmaf(w, xv.z, acc.z);
            acc.w = fmaf(w, xv.w, acc.w);
        }
    }
    acc.x += __shfl_xor(acc.x, 16, 64); acc.x += __shfl_xor(acc.x, 32, 64);
    acc.y += __shfl_xor(acc.y, 16, 64); acc.y += __shfl_xor(acc.y, 32, 64);
    acc.z += __shfl_xor(acc.z, 16, 64); acc.z += __shfl_xor(acc.z, 32, 64);
    acc.w += __shfl_xor(acc.w, 16, 64); acc.w += __shfl_xor(acc.w, 32, 64);
    s += __shfl_xor(s, 16, 64); s += __shfl_xor(s, 32, 64);

    if (g == 0) {
        float inv = 1.f / (s + 1e-16f);
        float4* op = (float4*)(hn + (size_t)d * HDIM);
        if (init) {
            op[c] = make_float4(acc.x * inv, acc.y * inv, acc.z * inv, acc.w * inv);
        } else {
            float4 old = op[c];
            op[c] = make_float4(old.x + acc.x * inv, old.y + acc.y * inv,
                                old.z + acc.z * inv, old.w + acc.w * inv);
        }
    }
}

// ---------------- epilogue ----------------

__global__ void bsum_kernel(const void* __restrict__ bias, const int* __restrict__ flag,
                            float* __restrict__ bsum)
{
    int bf = flag[0];
    int idx = threadIdx.x;  // 192 = 3*64
    if (idx >= 192) return;
    int nt = idx >> 6, h = idx & 63;
    float v;
    if (nt == 0)      v = ldf(bias, 0*64+h, bf) + ldf(bias, 1*64+h, bf) + ldf(bias, 4*64+h, bf);
    else if (nt == 1) v = ldf(bias, 2*64+h, bf) + ldf(bias, 5*64+h, bf);
    else              v = ldf(bias, 3*64+h, bf) + ldf(bias, 6*64+h, bf);
    bsum[idx] = v;
}

__global__ __launch_bounds__(256) void relu_kernel(
    const float* __restrict__ hn, const float* __restrict__ bsum,
    float* __restrict__ h, unsigned short* __restrict__ fbout)
{
    size_t idx = (size_t)blockIdx.x * 256 + threadIdx.x;
    if (idx >= (size_t)3 * N_NODES * HDIM) return;
    int nt = (int)(idx / ((size_t)N_NODES * HDIM));
    int hh = (int)(idx & 63);
    float v = hn[idx] + bsum[nt * 64 + hh];
    v = v > 0.f ? v : 0.f;
    h[idx] = v;
    if (fbout) fbout[idx] = f2bf(v);
}

__global__ __launch_bounds__(256) void head_kernel(
    const float* __restrict__ h0, const void* __restrict__ Wout,
    const void* __restrict__ bout, const int* __restrict__ flag,
    void* __restrict__ out)
{
    __shared__ float sW[64 * 4];
    __shared__ float sb[4];
    int bf = flag[0];
    int tid = threadIdx.x;
    sW[tid] = ldf(Wout, tid, bf);
    if (tid < 4) sb[tid] = ldf(bout, tid, bf);
    __syncthreads();
    int i = blockIdx.x * 256 + tid;
    if (i >= N_NODES) return;
    float l0 = sb[0], l1 = sb[1], l2 = sb[2], l3 = sb[3];
    const float4* p = (const float4*)(h0 + (size_t)i * HDIM);
    #pragma unroll
    for (int k = 0; k < 16; ++k) {
        float4 a = p[k];
        int d = 4 * k;
        l0 += a.x * sW[d*4+0] + a.y * sW[(d+1)*4+0] + a.z * sW[(d+2)*4+0] + a.w * sW[(d+3)*4+0];
        l1 += a.x * sW[d*4+1] + a.y * sW[(d+1)*4+1] + a.z * sW[(d+2)*4+1] + a.w * sW[(d+3)*4+1];
        l2 += a.x * sW[d*4+2] + a.y * sW[(d+1)*4+2] + a.z * sW[(d+2)*4+2] + a.w * sW[(d+3)*4+2];
        l3 += a.x * sW[d*4+3] + a.y * sW[(d+1)*4+3] + a.z * sW[(d+2)*4+3] + a.w * sW[(d+3)*4+3];
    }
    float m = fmaxf(fmaxf(l0, l1), fmaxf(l2, l3));
    float e0 = __expf(l0 - m), e1 = __expf(l1 - m), e2 = __expf(l2 - m), e3 = __expf(l3 - m);
    float inv = 1.f / (e0 + e1 + e2 + e3);
    if (bf) {
        bf16* o = (bf16*)out;
        o[(size_t)4*i + 0] = __float2bfloat16(e0 * inv);
        o[(size_t)4*i + 1] = __float2bfloat16(e1 * inv);
        o[(size_t)4*i + 2] = __float2bfloat16(e2 * inv);
        o[(size_t)4*i + 3] = __float2bfloat16(e3 * inv);
    } else {
        float* o = (float*)out;
        o[(size_t)4*i + 0] = e0 * inv;
        o[(size_t)4*i + 1] = e1 * inv;
        o[(size_t)4*i + 2] = e2 * inv;
        o[(size_t)4*i + 3] = e3 * inv;
    }
}

struct P2 { const void* b; const void* f; };
static inline P2 off2(const void* base, size_t elem) {
    P2 r;
    r.b = (const void*)((const bf16*)base + elem);
    r.f = (const void*)((const float*)base + elem);
    return r;
}

extern "C" void kernel_launch(void* const* d_in, const int* in_sizes, int n_in,
                              void* d_out, int out_size, void* d_ws, size_t ws_size,
                              hipStream_t stream)
{
    const void* x     = d_in[0];
    const int*  edges = (const int*)d_in[1];
    const void* Wl0 = d_in[2];
    const void* Wr0 = d_in[3];
    const void* bl0 = d_in[4];
    const void* br0 = d_in[5];
    const void* att0 = d_in[6];
    const void* bias0 = d_in[7];
    const void* Wl1 = d_in[8];
    const void* Wr1 = d_in[9];
    const void* bl1 = d_in[10];
    const void* br1 = d_in[11];
    const void* att1 = d_in[12];
    const void* bias1 = d_in[13];
    const void* Wout = d_in[14];
    const void* bout = d_in[15];

    const int SRCt[7] = {0, 1, 1, 1, 2, 2, 2};
    const int DSTt[7] = {0, 0, 1, 2, 0, 1, 2};

    // ---- workspace layout ----
    float* h3  = (float*)d_ws;                                  // 3*N*H
    float* hn3 = h3 + (size_t)3 * N_NODES * HDIM;               // 3*N*H (38.4 MB)
    unsigned short* xl = (unsigned short*)(hn3 + (size_t)3 * N_NODES * HDIM); // N*H bf16
    unsigned short* xr = xl + (size_t)N_NODES * HDIM;           // N*H bf16
    char* tail = (char*)(xl + (size_t)2 * N_NODES * HDIM) + (size_t)2 * N_NODES * HDIM * 2;

    size_t fixed = (size_t)tail - (size_t)d_ws;
    size_t base_need = fixed + ((size_t)NROWS + 1) * 4 + (size_t)7 * NEDGE * 4
                     + (NCB + 1) * 4 + 2 * 256 * 4 + 192 * 4 + 4
                     + 2 * (size_t)N_NODES * 4 + 512;
    size_t mfma_extra = (size_t)3 * N_NODES * HDIM * 2
                      + (size_t)7 * 2 * 64 * HDIM * 2
                      + (size_t)7 * 2 * 64 * DIN * 2 + 512;
    bool full = ws_size >= base_need;
    bool mfma_ok = ws_size >= base_need + mfma_extra;
    int NT = full ? 7 : 1;

    int* P        = (int*)tail;                                 // NT*N+1
    int* col_src  = P + ((size_t)NT * N_NODES + 1);             // NT*E
    int* cbase    = col_src + (size_t)NT * NEDGE;               // NCB+1
    int* bsums    = cbase + (NCB + 1);                          // 256
    int* boffs    = bsums + 256;                                // 256
    float* bsum   = (float*)(boffs + 256);                      // 192
    int* flag     = (int*)(bsum + 192);                         // 1
    int* cnt      = flag + 1;                                   // N (fallback)
    int* cursor   = cnt + N_NODES;                              // N (fallback)
    unsigned short* fb  = (unsigned short*)(((size_t)(cursor + N_NODES) + 255) & ~(size_t)255);
    unsigned short* wt1 = fb + (size_t)3 * N_NODES * HDIM;
    unsigned short* wt0 = wt1 + (size_t)7 * 2 * 64 * HDIM;

    unsigned* buf = (unsigned*)hn3;                             // 7E (22.4 MB)
    int* cnt2d    = (int*)(buf + (size_t)7 * NEDGE);            // NCB*NBLK1 (1.87 MB)

    dim3 blk(256);
    int gLin  = (N_NODES + 31) / 32;
    int gGemm = (N_NODES + 63) / 64;
    int gRow  = (N_NODES + 3) / 4;
    int gRelu = (int)(((size_t)3 * N_NODES * HDIM + 255) / 256);
    int gHead = (N_NODES + 255) / 256;

    detect_kernel<<<1, 256, 0, stream>>>((const unsigned short*)x, flag);

    if (full) {
        k1_count_kernel<<<NBLK1, 1024, 0, stream>>>(edges, cnt2d);
        k2_colscan_kernel<<<NCB, blk, 0, stream>>>(cnt2d, cbase);
        k3_cscan_kernel<<<1, blk, 0, stream>>>(cbase, P);
        part1_kernel<<<NBLK1, 1024, 0, stream>>>(edges, cnt2d, cbase, buf);
        part2_kernel<<<NCB, blk, 0, stream>>>(buf, cbase, P, col_src);
    }

    for (int layer = 0; layer < 2; ++layer) {
        const void* Wl = layer ? Wl1 : Wl0;
        const void* Wr = layer ? Wr1 : Wr0;
        const void* bl = layer ? bl1 : bl0;
        const void* br = layer ? br1 : br0;
        const void* at = layer ? att1 : att0;
        const void* bi = layer ? bias1 : bias0;
        int K = layer ? HDIM : DIN;

        bsum_kernel<<<1, 192, 0, stream>>>(bi, flag, bsum);

        if (mfma_ok) {
            if (layer == 0) {
                size_t nfeat = (size_t)3 * N_NODES * DIN;
                cvt_feat_kernel<<<(int)((nfeat / 4 + 255) / 256), blk, 0, stream>>>(
                    x, -1, flag, fb, nfeat);
            }
            unsigned short* wt = layer ? wt1 : wt0;
            cvt_w_kernel<<<dim3(7, 2), blk, 0, stream>>>(
                off2(Wl, 0).b, off2(Wl, 0).f, off2(Wr, 0).b, off2(Wr, 0).f, flag, wt, K);
        }

        for (int t = 0; t < 7; ++t) {
            const int* rp;
            const int* cs;
            if (full) {
                rp = P + (size_t)t * N_NODES;
                cs = col_src;
            } else {
                const int* et = edges + (size_t)t * 2 * NEDGE;
                int n = N_NODES;
                int nb = (n + 2047) / 2048;
                int gE1 = (NEDGE + 255) / 256;
                hipMemsetAsync(cnt, 0, (size_t)n * sizeof(int), stream);
                hist_kernel<<<gE1, blk, 0, stream>>>(et, cnt, 1);
                scanA_kernel<<<nb, blk, 0, stream>>>(cnt, bsums, n);
                scanB_kernel<<<1, blk, 0, stream>>>(bsums, boffs, nb, P, n);
                scanC_kernel<<<nb, blk, 0, stream>>>(cnt, boffs, P, cursor, n);
                scatter1_kernel<<<gE1, blk, 0, stream>>>(et, cursor, col_src);
                rp = P;
                cs = col_src;
            }

            P2 bL = off2(bl, (size_t)t * HDIM);
            P2 bR = off2(br, (size_t)t * HDIM);
            if (mfma_ok) {
                unsigned short* wt = (layer ? wt1 : wt0) + (size_t)t * 2 * 64 * K;
                if (layer == 0)
                    gemm_lin_t<DIN><<<dim3(gGemm, 2), blk, 0, stream>>>(
                        fb, SRCt[t], DSTt[t], wt, bL.b, bL.f, bR.b, bR.f, flag, xl, xr);
                else
                    gemm_lin_t<HDIM><<<dim3(gGemm, 2), blk, 0, stream>>>(
                        fb, SRCt[t], DSTt[t], wt, bL.b, bL.f, bR.b, bR.f, flag, xl, xr);
            } else if (layer == 0) {
                P2 fs = off2(x, (size_t)SRCt[t] * N_NODES * DIN);
                P2 fd = off2(x, (size_t)DSTt[t] * N_NODES * DIN);
                P2 wl = off2(Wl, (size_t)t * DIN * HDIM);
                P2 wr = off2(Wr, (size_t)t * DIN * HDIM);
                lin_d32_t<0><<<dim3(gLin, 2), blk, 0, stream>>>(
                    fs.b, fs.f, fd.b, fd.f, wl.b, wl.f, wr.b, wr.f,
                    bL.b, bL.f, bR.b, bR.f, flag, xl, xr);
                lin_d32_t<1><<<dim3(gLin, 2), blk, 0, stream>>>(
                    fs.b, fs.f, fd.b, fd.f, wl.b, wl.f, wr.b, wr.f,
                    bL.b, bL.f, bR.b, bR.f, flag, xl, xr);
            } else {
                P2 wl = off2(Wl, (size_t)t * HDIM * HDIM);
                P2 wr = off2(Wr, (size_t)t * HDIM * HDIM);
                const float* fL = h3 + (size_t)SRCt[t] * N_NODES * HDIM;
                const float* fR = h3 + (size_t)DSTt[t] * N_NODES * HDIM;
                lin_d64_t<0><<<dim3(gLin, 2), blk, 0, stream>>>(
                    fL, fR, wl.b, wl.f, wr.b, wr.f, bL.b, bL.f, bR.b, bR.f, flag, xl, xr);
                lin_d64_t<1><<<dim3(gLin, 2), blk, 0, stream>>>(
                    fL, fR, wl.b, wl.f, wr.b, wr.f, bL.b, bL.f, bR.b, bR.f, flag, xl, xr);
            }

            int init = (t == 0 || t == 2 || t == 3) ? 1 : 0;
            P2 a2 = off2(at, (size_t)t * HDIM);
            gat_row_kernel<<<gRow, blk, 0, stream>>>(rp, cs, xl, xr,
                                                     a2.b, a2.f, flag,
                                                     hn3 + (size_t)DSTt[t] * N_NODES * HDIM,
                                                     init);
        }
        relu_kernel<<<gRelu, blk, 0, stream>>>(hn3, bsum, h3,
                                               (mfma_ok && layer == 0) ? fb : (unsigned short*)nullptr);
    }

    head_kernel<<<gHead, blk, 0, stream>>>(h3, Wout, bout, flag, d_out);
}